// Round 1
// 167.089 us; speedup vs baseline: 1.0058x; 1.0058x over previous
//
#include <hip/hip_runtime.h>
#include <hip/hip_bf16.h>

// Problem: N=10000, E=320000, FIN=512, FH=128, FOUT=40.
// Restructured 4-dispatch pipeline (was 5) to hide the CSR-fill atomics:
//  D0 k_init      : zero cnt/regp | pack W1 hi/lo | pack W2 hi/lo   (no upstream dep)
//  D1 k_gemm_fill : [fill] csr[d*CAP + atomicAdd(cnt[d])] = src  (FIRST in grid)
//                   [gemm] H(bf16, UNSCALED) = X(fp32, inline cvt) @ W1, M-tile 64
//                   gemm consumes nothing from fill -> atomics overlap the GEMM.
//  D2 k_agg1_reg  : wave/node: AGG1 = relu(dinv[d]*(Σ dinv[s]H[s] + dinv[d]H[d]) + b1)
//                   dinv[s] computed in-gather (broadcast cnt[s] + rsqrt);
//                   wave 0: fused GEMM2 -> LG' = dinv[d]*(AGG1@W2) (bf16, stride 48)
//                   + co-launched reg-scan blocks (need csr complete = D1).
//  D3 k_agg2_lsm  : out = log_softmax(dinv[d]*(Σ LG'[s] + LG'[d]) + b2); out[N*F] = reg

#define CAP 128

typedef __attribute__((ext_vector_type(8))) short short8;   // 8 x bf16 (4 VGPRs)
typedef __attribute__((ext_vector_type(4))) float float4v;  // MFMA C/D

__device__ __forceinline__ unsigned short f2bf(float f) {
    __hip_bfloat16 b = __float2bfloat16(f);
    return *reinterpret_cast<unsigned short*>(&b);
}
__device__ __forceinline__ float bf2f(unsigned short u) {
    __hip_bfloat16 b = *reinterpret_cast<__hip_bfloat16*>(&u);
    return __bfloat162float(b);
}
__device__ __forceinline__ float blo(unsigned u) { return __uint_as_float(u << 16); }
__device__ __forceinline__ float bhi(unsigned u) { return __uint_as_float(u & 0xffff0000u); }

__device__ __forceinline__ short8 cvt8(float4 f0, float4 f1) {
    short8 r;
    r[0] = (short)f2bf(f0.x); r[1] = (short)f2bf(f0.y);
    r[2] = (short)f2bf(f0.z); r[3] = (short)f2bf(f0.w);
    r[4] = (short)f2bf(f1.x); r[5] = (short)f2bf(f1.y);
    r[6] = (short)f2bf(f1.z); r[7] = (short)f2bf(f1.w);
    return r;
}

// ---- D0: zero cnt/regp | pack W1 hi/lo | pack W2 hi/lo ----
__global__ void k_init(int* __restrict__ cnt, float* __restrict__ regp, int Nn,
                       const float* __restrict__ W1, unsigned short* __restrict__ Bh1,
                       unsigned short* __restrict__ Bl1,
                       const float* __restrict__ W2, unsigned short* __restrict__ Bh2,
                       unsigned short* __restrict__ Bl2,
                       int zeroB, int p1B) {
    int b = blockIdx.x;
    if (b < zeroB) {
        int i = b * 256 + threadIdx.x;
        if (i < Nn) cnt[i] = 0;
        if (b == 0 && threadIdx.x < 16) regp[threadIdx.x] = 0.f;
        return;
    }
    b -= zeroB;
    if (b < p1B) {   // pack W1: KB=16, NF=8, N=128
        int t = b * 256 + threadIdx.x;
        int lane = t & 63;
        int f = (t >> 6) % 8;
        int kb = (t >> 6) / 8;
        int kbase = kb * 32 + (lane >> 4) * 8;
        int n = f * 16 + (lane & 15);
        unsigned short hj[8], lj[8];
#pragma unroll
        for (int j = 0; j < 8; j++) {
            float v = W1[(size_t)(kbase + j) * 128 + n];
            unsigned short hb = f2bf(v);
            hj[j] = hb;
            lj[j] = f2bf(v - bf2f(hb));
        }
        ushort4 h0 = {hj[0], hj[1], hj[2], hj[3]}, h1 = {hj[4], hj[5], hj[6], hj[7]};
        ushort4 l0 = {lj[0], lj[1], lj[2], lj[3]}, l1 = {lj[4], lj[5], lj[6], lj[7]};
        ((ushort4*)Bh1)[t * 2] = h0; ((ushort4*)Bh1)[t * 2 + 1] = h1;
        ((ushort4*)Bl1)[t * 2] = l0; ((ushort4*)Bl1)[t * 2 + 1] = l1;
        return;
    }
    b -= p1B;
    {   // pack W2: KB=4, NF=3 (48 padded, real N=40)
        int t = b * 256 + threadIdx.x;
        if (t >= 4 * 3 * 64) return;
        int lane = t & 63;
        int f = (t >> 6) % 3;
        int kb = (t >> 6) / 3;
        int kbase = kb * 32 + (lane >> 4) * 8;
        int n = f * 16 + (lane & 15);
        unsigned short hj[8], lj[8];
#pragma unroll
        for (int j = 0; j < 8; j++) {
            float v = (n < 40) ? W2[(size_t)(kbase + j) * 40 + n] : 0.f;
            unsigned short hb = f2bf(v);
            hj[j] = hb;
            lj[j] = f2bf(v - bf2f(hb));
        }
        ushort4 h0 = {hj[0], hj[1], hj[2], hj[3]}, h1 = {hj[4], hj[5], hj[6], hj[7]};
        ushort4 l0 = {lj[0], lj[1], lj[2], lj[3]}, l1 = {lj[4], lj[5], lj[6], lj[7]};
        ((ushort4*)Bh2)[t * 2] = h0; ((ushort4*)Bh2)[t * 2 + 1] = h1;
        ((ushort4*)Bl2)[t * 2] = l0; ((ushort4*)Bl2)[t * 2 + 1] = l1;
    }
}

// ---- D1: [fill blocks first] CSR fill (4 edges/thread) || [gemm] H = X@W1 (unscaled)
//          A read fp32 + in-register bf16 cvt; B LDS dbuf; M-tile 64, 256 thr ----
__global__ __launch_bounds__(256)
void k_gemm_fill(const float* __restrict__ x,
                 const unsigned short* __restrict__ Bh, const unsigned short* __restrict__ Bl,
                 unsigned short* __restrict__ H0, int M,
                 const int* __restrict__ src, const int* __restrict__ dst, int E,
                 int* __restrict__ cnt, unsigned short* __restrict__ csr, int fillB) {
    if ((int)blockIdx.x < fillB) {
        int base = blockIdx.x * 1024 + threadIdx.x;
#pragma unroll
        for (int it = 0; it < 4; it++) {
            int e = base + it * 256;
            if (e < E) {
                int d = dst[e];
                int pos = atomicAdd(&cnt[d], 1);
                if (pos < CAP) csr[(size_t)d * CAP + pos] = (unsigned short)src[e];
            }
        }
        return;
    }
    const int NF = 8, KB = 16, K = 512;
    const int CH = NF * 64;                       // 512 uint4 per (hi|lo) per kb
    __shared__ uint4 sB[2][2 * NF * 64];          // 32 KB
    int bb = (int)blockIdx.x - fillB;
    int w = threadIdx.x >> 6, lane = threadIdx.x & 63;
    int m0 = bb * 64 + w * 16;
    bool valid = (m0 < M);
    int arow = valid ? (m0 + (lane & 15)) : 0;

    const uint4* GH = (const uint4*)Bh;
    const uint4* GL = (const uint4*)Bl;
    float4v acc[NF] = {};
    const float4* A = (const float4*)(x + (size_t)arow * K) + (lane >> 4) * 2;

#pragma unroll
    for (int c = threadIdx.x; c < CH; c += 256) {
        sB[0][c] = GH[c];
        sB[0][CH + c] = GL[c];
    }
    float4 f0 = A[0], f1 = A[1];
    short8 a = cvt8(f0, f1);
    __syncthreads();

    for (int kb = 0; kb < KB; kb++) {
        int slot = kb & 1;
        if (kb + 1 < KB) {
            const uint4* gh = GH + (kb + 1) * CH;
            const uint4* gl = GL + (kb + 1) * CH;
#pragma unroll
            for (int c = threadIdx.x; c < CH; c += 256) {
                sB[slot ^ 1][c] = gh[c];
                sB[slot ^ 1][CH + c] = gl[c];
            }
            f0 = A[(kb + 1) * 8];
            f1 = A[(kb + 1) * 8 + 1];
        }
        const short8* sb = (const short8*)sB[slot];
#pragma unroll
        for (int f = 0; f < NF; f++) {
            short8 bh = sb[f * 64 + lane];
            short8 bl = sb[CH + f * 64 + lane];
            acc[f] = __builtin_amdgcn_mfma_f32_16x16x32_bf16(a, bh, acc[f], 0, 0, 0);
            acc[f] = __builtin_amdgcn_mfma_f32_16x16x32_bf16(a, bl, acc[f], 0, 0, 0);
        }
        if (kb + 1 < KB) a = cvt8(f0, f1);
        __syncthreads();
    }
    if (!valid) return;
    int row = (lane >> 4) * 4, col = lane & 15;
#pragma unroll
    for (int f = 0; f < NF; f++)
#pragma unroll
        for (int r = 0; r < 4; r++)
            H0[(size_t)(m0 + row + r) * 128 + f * 16 + col] = f2bf(acc[f][r]);
}

// ---- D2: [agg blocks first] 16 waves/block, wave per node; dinv[s] in-gather.
//          wave 0: fused GEMM2. + [reg blocks] 4-lane-group CSR count, 2048 e/block ----
__global__ __launch_bounds__(1024)
void k_agg1_reg(const int* __restrict__ cnt, const unsigned short* __restrict__ csr,
                const unsigned short* __restrict__ H, const float* __restrict__ b1,
                const unsigned short* __restrict__ Bh2, const unsigned short* __restrict__ Bl2,
                unsigned short* __restrict__ LGb, int Nn,
                const int* __restrict__ src, const int* __restrict__ dst, int E,
                float* __restrict__ regp, int aggB) {
    if ((int)blockIdx.x >= aggB) {
        // reg: group of 4 lanes per edge; each lane strides 32 entries of csr row
        int b = (int)blockIdx.x - aggB;
        int g = threadIdx.x >> 2;          // 0..255
        int sub = threadIdx.x & 3;
        int base = b * 2048;
        int c = 0;
        for (int it = 0; it < 8; it++) {
            int e = base + it * 256 + g;
            if (e < E) {
                int s = src[e];
                unsigned d = (unsigned)dst[e];
                int len = min(cnt[s], CAP);
                const unsigned short* row = csr + (size_t)s * CAP;
                for (int i = sub * 8; i < len; i += 32) {
                    uint4 v = *(const uint4*)(row + i);
                    c += ((v.x & 0xffffu) == d) ? 1 : 0;
                    c += ((v.x >> 16) == d && i + 1 < len) ? 1 : 0;
                    c += ((v.y & 0xffffu) == d && i + 2 < len) ? 1 : 0;
                    c += ((v.y >> 16) == d && i + 3 < len) ? 1 : 0;
                    c += ((v.z & 0xffffu) == d && i + 4 < len) ? 1 : 0;
                    c += ((v.z >> 16) == d && i + 5 < len) ? 1 : 0;
                    c += ((v.w & 0xffffu) == d && i + 6 < len) ? 1 : 0;
                    c += ((v.w >> 16) == d && i + 7 < len) ? 1 : 0;
                }
            }
        }
#pragma unroll
        for (int off = 32; off; off >>= 1) c += __shfl_xor(c, off, 64);
        if ((threadIdx.x & 63) == 0 && c) atomicAdd(regp, (float)c);
        return;
    }
    __shared__ unsigned rowbuf[16 * 68];   // 16 rows x 128 bf16 (pairs), stride 68
    __shared__ float sdd[16];
    int w = threadIdx.x >> 6, lane = threadIdx.x & 63;
    int wid = blockIdx.x * 16 + w;
    if (wid < Nn) {
        int len = min(cnt[wid], CAP);
        float dd = rsqrtf((float)len + 1.0f);
        const unsigned* H2 = (const unsigned*)H;   // bf16x2 per lane
        unsigned ph = H2[((unsigned)wid << 6) + lane];
        float ax0 = dd * blo(ph), ax1 = 0.f, ax2 = 0.f, ax3 = 0.f;   // self: dinv[d]*H[d]
        float ay0 = dd * bhi(ph), ay1 = 0.f, ay2 = 0.f, ay3 = 0.f;
        const unsigned short* row = csr + (size_t)wid * CAP;
        int j = 0;
        if (len >= 8) {
            uint4 iv = *(const uint4*)(row);
            for (; j + 8 <= len; j += 8) {
                uint4 ivn = iv;
                if (j + 16 <= len) ivn = *(const uint4*)(row + j + 8);
                unsigned s0 = iv.x & 0xffffu, s1 = iv.x >> 16;
                unsigned s2 = iv.y & 0xffffu, s3 = iv.y >> 16;
                unsigned s4 = iv.z & 0xffffu, s5 = iv.z >> 16;
                unsigned s6 = iv.w & 0xffffu, s7 = iv.w >> 16;
                unsigned p0 = H2[(s0 << 6) + lane], p1 = H2[(s1 << 6) + lane];
                unsigned p2 = H2[(s2 << 6) + lane], p3 = H2[(s3 << 6) + lane];
                unsigned p4 = H2[(s4 << 6) + lane], p5 = H2[(s5 << 6) + lane];
                unsigned p6 = H2[(s6 << 6) + lane], p7 = H2[(s7 << 6) + lane];
                int c0 = cnt[s0], c1 = cnt[s1], c2 = cnt[s2], c3 = cnt[s3];
                int c4 = cnt[s4], c5 = cnt[s5], c6 = cnt[s6], c7 = cnt[s7];
                float d0 = rsqrtf((float)min(c0, CAP) + 1.0f);
                float d1 = rsqrtf((float)min(c1, CAP) + 1.0f);
                float d2 = rsqrtf((float)min(c2, CAP) + 1.0f);
                float d3 = rsqrtf((float)min(c3, CAP) + 1.0f);
                float d4 = rsqrtf((float)min(c4, CAP) + 1.0f);
                float d5 = rsqrtf((float)min(c5, CAP) + 1.0f);
                float d6 = rsqrtf((float)min(c6, CAP) + 1.0f);
                float d7 = rsqrtf((float)min(c7, CAP) + 1.0f);
                ax0 = fmaf(d0, blo(p0), ax0); ay0 = fmaf(d0, bhi(p0), ay0);
                ax1 = fmaf(d1, blo(p1), ax1); ay1 = fmaf(d1, bhi(p1), ay1);
                ax2 = fmaf(d2, blo(p2), ax2); ay2 = fmaf(d2, bhi(p2), ay2);
                ax3 = fmaf(d3, blo(p3), ax3); ay3 = fmaf(d3, bhi(p3), ay3);
                ax0 = fmaf(d4, blo(p4), ax0); ay0 = fmaf(d4, bhi(p4), ay0);
                ax1 = fmaf(d5, blo(p5), ax1); ay1 = fmaf(d5, bhi(p5), ay1);
                ax2 = fmaf(d6, blo(p6), ax2); ay2 = fmaf(d6, bhi(p6), ay2);
                ax3 = fmaf(d7, blo(p7), ax3); ay3 = fmaf(d7, bhi(p7), ay3);
                iv = ivn;
            }
        }
        for (; j < len; j++) {
            unsigned sv = row[j];
            unsigned p0 = H2[(sv << 6) + lane];
            float dq = rsqrtf((float)min(cnt[sv], CAP) + 1.0f);
            ax0 = fmaf(dq, blo(p0), ax0);
            ay0 = fmaf(dq, bhi(p0), ay0);
        }
        float accx = (ax0 + ax1) + (ax2 + ax3);
        float accy = (ay0 + ay1) + (ay2 + ay3);
        float2 bb = ((const float2*)b1)[lane];
        float vx = dd * accx + bb.x, vy = dd * accy + bb.y;
        vx = vx > 0.f ? vx : 0.f;
        vy = vy > 0.f ? vy : 0.f;
        rowbuf[w * 68 + lane] = (unsigned)f2bf(vx) | ((unsigned)f2bf(vy) << 16);
        if (lane == 0) sdd[w] = dd;
    }
    __syncthreads();
    if (w == 0) {
        // fused GEMM2: LG'[m][f] = sdd[m] * (AGG1row[m] @ W2)
        float4v acc2[3] = {};
        const short8* BH = ((const short8*)Bh2) + lane;
        const short8* BL = ((const short8*)Bl2) + lane;
        int m = lane & 15, quad = lane >> 4;
#pragma unroll
        for (int kb = 0; kb < 4; kb++) {
            const unsigned* ap = &rowbuf[m * 68 + kb * 16 + quad * 4];
            short8 a = *reinterpret_cast<const short8*>(ap);
#pragma unroll
            for (int f = 0; f < 3; f++) {
                short8 bh = BH[(kb * 3 + f) * 64];
                short8 bl = BL[(kb * 3 + f) * 64];
                acc2[f] = __builtin_amdgcn_mfma_f32_16x16x32_bf16(a, bh, acc2[f], 0, 0, 0);
                acc2[f] = __builtin_amdgcn_mfma_f32_16x16x32_bf16(a, bl, acc2[f], 0, 0, 0);
            }
        }
        int col = lane & 15, rbase = (lane >> 4) * 4;
#pragma unroll
        for (int f = 0; f < 3; f++)
#pragma unroll
            for (int r = 0; r < 4; r++) {
                int node = rbase + r;
                int g = blockIdx.x * 16 + node;
                if (g < Nn)
                    LGb[(size_t)g * 48 + f * 16 + col] = f2bf(acc2[f][r] * sdd[node]);
            }
    }
}

// ---- D3: pure-sum gather over LG' (bf16, stride 48) + bias + log_softmax ----
__global__ void k_agg2_lsm(const int* __restrict__ cnt, const unsigned short* __restrict__ csr,
                           const unsigned short* __restrict__ LGb, const float* __restrict__ b2,
                           const float* __restrict__ regp, float* __restrict__ out,
                           int Nn, int F) {
    int wid = (int)(blockIdx.x * blockDim.x + threadIdx.x) >> 6;
    int lane = threadIdx.x & 63;
    if (wid >= Nn) return;
    int len = min(cnt[wid], CAP);
    bool act = lane < F;
    float a0c = act ? bf2f(LGb[(unsigned)wid * 48 + lane]) : 0.f;   // self-loop
    float a1c = 0.f, a2c = 0.f, a3c = 0.f;
    const unsigned short* row = csr + (size_t)wid * CAP;
    int j = 0;
    for (; j + 8 <= len; j += 8) {
        uint4 idv = *(const uint4*)(row + j);
        unsigned s[8];
        s[0] = idv.x & 0xffff; s[1] = idv.x >> 16; s[2] = idv.y & 0xffff; s[3] = idv.y >> 16;
        s[4] = idv.z & 0xffff; s[5] = idv.z >> 16; s[6] = idv.w & 0xffff; s[7] = idv.w >> 16;
        unsigned short a[8];
#pragma unroll
        for (int q = 0; q < 8; q++) a[q] = act ? LGb[s[q] * 48 + lane] : (unsigned short)0;
        a0c += __uint_as_float((unsigned)a[0] << 16);
        a1c += __uint_as_float((unsigned)a[1] << 16);
        a2c += __uint_as_float((unsigned)a[2] << 16);
        a3c += __uint_as_float((unsigned)a[3] << 16);
        a0c += __uint_as_float((unsigned)a[4] << 16);
        a1c += __uint_as_float((unsigned)a[5] << 16);
        a2c += __uint_as_float((unsigned)a[6] << 16);
        a3c += __uint_as_float((unsigned)a[7] << 16);
    }
    for (; j < len; j++) {
        unsigned short a0 = act ? LGb[(unsigned)row[j] * 48 + lane] : (unsigned short)0;
        a0c += __uint_as_float((unsigned)a0 << 16);
    }
    float acc = (a0c + a1c) + (a2c + a3c);
    float dd = rsqrtf((float)len + 1.0f);
    float v = act ? dd * acc + b2[lane] : -1e30f;
    float m = v;
#pragma unroll
    for (int off = 32; off; off >>= 1) m = fmaxf(m, __shfl_xor(m, off, 64));
    float ex = act ? expf(v - m) : 0.f;
    float ssum = ex;
#pragma unroll
    for (int off = 32; off; off >>= 1) ssum += __shfl_xor(ssum, off, 64);
    if (act) out[(size_t)wid * F + lane] = v - m - logf(ssum);
    if (wid == 0 && lane == 0) out[(size_t)Nn * F] = regp[0];
}

extern "C" void kernel_launch(void* const* d_in, const int* in_sizes, int n_in,
                              void* d_out, int out_size, void* d_ws, size_t ws_size,
                              hipStream_t stream) {
    const float* x  = (const float*)d_in[0];
    const int*   ei = (const int*)d_in[1];
    const float* W1 = (const float*)d_in[2];
    const float* b1 = (const float*)d_in[3];
    const float* W2 = (const float*)d_in[4];
    const float* b2 = (const float*)d_in[5];
    float* out = (float*)d_out;

    const int FH   = in_sizes[3];            // 128
    const int FOUT = in_sizes[5];            // 40
    const int FIN  = in_sizes[2] / FH;       // 512
    const int Nn   = in_sizes[0] / FIN;      // 10000
    const int E    = in_sizes[1] / 2;        // 320000
    const int* src = ei;
    const int* dst = ei + E;

    // ---- workspace layout (Xh dropped; all bases 16B-aligned) ----
    int*   cnt  = (int*)d_ws;                                 // Nn
    float* regp = (float*)(cnt + Nn);                         // 16 (1 used)
    unsigned short* csr   = (unsigned short*)(regp + 16);     // Nn*CAP
    unsigned short* H0b   = csr + (size_t)Nn * CAP;           // Nn*FH
    unsigned short* Bh1   = H0b + (size_t)Nn * FH;            // 65536
    unsigned short* Bl1   = Bh1 + 65536;
    unsigned short* Bh2   = Bl1 + 65536;                      // 6144
    unsigned short* Bl2   = Bh2 + 6144;
    unsigned short* LGb   = Bl2 + 6144;                       // Nn*48

    // D0: zero cnt/regp + pack W1 + pack W2 (replaces memset dispatch)
    int zeroB = (Nn + 255) / 256;              // 40
    int p1B = (16 * 8 * 64) / 256;             // 32
    int p2B = (4 * 3 * 64 + 255) / 256;        // 3
    k_init<<<zeroB + p1B + p2B, 256, 0, stream>>>(
        cnt, regp, Nn, W1, Bh1, Bl1, W2, Bh2, Bl2, zeroB, p1B);

    // D1: CSR fill (first, 4 edges/thread) co-launched with GEMM1 (no fill dep)
    int fillB = (E + 1023) / 1024;             // 313
    int gemmB = (Nn + 63) / 64;                // 157
    k_gemm_fill<<<fillB + gemmB, 256, 0, stream>>>(
        x, Bh1, Bl1, H0b, Nn, src, dst, E, cnt, csr, fillB);

    // D2: agg1 (dinv-in-gather) + fused GEMM2, co-launched with reg scan
    int aggB = (Nn + 15) / 16;                 // 625
    int regB = (E + 2047) / 2048;              // 157
    k_agg1_reg<<<aggB + regB, 1024, 0, stream>>>(
        cnt, csr, H0b, b1, Bh2, Bl2, LGb, Nn, src, dst, E, regp, aggB);

    // D3: out = log_softmax(dinv*(sum LG') + b2); out[N*F] = reg
    k_agg2_lsm<<<(Nn * 64 + 255) / 256, 256, 0, stream>>>(
        cnt, csr, LGb, b2, regp, out, Nn, FOUT);
}